// Round 2
// baseline (90.624 us; speedup 1.0000x reference)
//
#include <hip/hip_runtime.h>

#define BN 512   // batch
#define DD 512   // feature dim
#define LL 24    // label dim

__device__ __forceinline__ float dist_val(float d2, bool diag) {
    d2 = fmaxf(d2, 0.0f);
    float d = sqrtf(d2);
    return diag ? 0.0f : d;
}

// ws layout (as float words):
//   [0, 512)              : masks (u32)
//   [512, 512 + 512*512)  : Dm (f32)
//   then accum: [0]=sum(f32), [1]=cnt(u32), [2]=done(u32)

// ---------------- kernel 1: dist (+ fused norms, masks, accum zero) ----------
__global__ __launch_bounds__(256) void dist_prep_kernel(
    const float* __restrict__ S, const int* __restrict__ labels,
    unsigned* __restrict__ masks, float* __restrict__ Dm, float* __restrict__ accum)
{
    __shared__ float As[32][34];
    __shared__ float Bs[32][34];
    __shared__ float nrmA[32], nrmB[32];
    const int t  = threadIdx.x;
    const int tx = t & 15, ty = t >> 4;
    const int jb = blockIdx.x * 32;
    const int ib = blockIdx.y * 32;
    const int lr = t >> 3;          // tile row 0..31
    const int lc = (t & 7) * 4;     // k-chunk offset 0,4,...,28

    if (blockIdx.x == 0 && blockIdx.y == 0) {
        // label bitmasks + zero accumulators (done by one block; visible to
        // kernel 2 via the kernel boundary)
        for (int r = t; r < BN; r += 256) {
            const int* lab = labels + r * LL;
            unsigned m = 0;
#pragma unroll
            for (int l = 0; l < LL; l++) m |= (lab[l] != 0 ? 1u : 0u) << l;
            masks[r] = m;
        }
        if (t == 0) {
            accum[0] = 0.0f;
            ((unsigned*)accum)[1] = 0u;   // count
            ((unsigned*)accum)[2] = 0u;   // done counter
        }
    }

    const float* Ap = S + (size_t)(ib + lr) * DD + lc;
    const float* Bp = S + (size_t)(jb + lr) * DD + lc;
    float4 a = *(const float4*)Ap;      // k-tile 0
    float4 b = *(const float4*)Bp;
    float na = 0.f, nb = 0.f;
    float acc00 = 0.f, acc01 = 0.f, acc10 = 0.f, acc11 = 0.f;

    for (int k0 = 0; k0 < DD; k0 += 32) {
        As[lc+0][lr]=a.x; As[lc+1][lr]=a.y; As[lc+2][lr]=a.z; As[lc+3][lr]=a.w;
        Bs[lc+0][lr]=b.x; Bs[lc+1][lr]=b.y; Bs[lc+2][lr]=b.z; Bs[lc+3][lr]=b.w;
        na += a.x*a.x + a.y*a.y + a.z*a.z + a.w*a.w;
        nb += b.x*b.x + b.y*b.y + b.z*b.z + b.w*b.w;
        __syncthreads();
        float4 a1 = make_float4(0.f,0.f,0.f,0.f), b1 = a1;
        if (k0 + 32 < DD) {             // prefetch next tile over the FMA loop
            a1 = *(const float4*)(Ap + k0 + 32);
            b1 = *(const float4*)(Bp + k0 + 32);
        }
#pragma unroll
        for (int kk = 0; kk < 32; kk++) {
            float2 av = *(const float2*)&As[kk][ty * 2];
            float2 bv = *(const float2*)&Bs[kk][tx * 2];
            acc00 += av.x * bv.x; acc01 += av.x * bv.y;
            acc10 += av.y * bv.x; acc11 += av.y * bv.y;
        }
        __syncthreads();
        a = a1; b = b1;
    }

    // per-row norms: 8 consecutive lanes (t&7) hold partials of row lr
    na += __shfl_down(na, 4, 8); na += __shfl_down(na, 2, 8); na += __shfl_down(na, 1, 8);
    nb += __shfl_down(nb, 4, 8); nb += __shfl_down(nb, 2, 8); nb += __shfl_down(nb, 1, 8);
    if ((t & 7) == 0) { nrmA[lr] = na; nrmB[lr] = nb; }
    __syncthreads();

    const int i0 = ib + ty * 2, j0 = jb + tx * 2;
    const float ni0 = nrmA[ty*2], ni1 = nrmA[ty*2+1];
    const float nj0 = nrmB[tx*2], nj1 = nrmB[tx*2+1];
    float2 r0, r1;
    r0.x = dist_val(ni0 + nj0 - 2.f * acc00, i0     == j0    );
    r0.y = dist_val(ni0 + nj1 - 2.f * acc01, i0     == j0 + 1);
    r1.x = dist_val(ni1 + nj0 - 2.f * acc10, i0 + 1 == j0    );
    r1.y = dist_val(ni1 + nj1 - 2.f * acc11, i0 + 1 == j0 + 1);
    *(float2*)&Dm[(size_t)i0 * BN + j0]       = r0;
    *(float2*)&Dm[(size_t)(i0+1) * BN + j0]   = r1;
}

// ---------------- kernel 2: triplet pairs + last-block finalize --------------
__global__ __launch_bounds__(256) void triplet_final_kernel(
    const float* __restrict__ Dm, const unsigned* __restrict__ masks,
    float* __restrict__ accum, float* __restrict__ out)
{
    __shared__ float pos[BN];
    __shared__ float neg[BN];
    __shared__ int pcnt, ncnt;
    __shared__ float wsum[4];
    __shared__ unsigned wcnt[4];
    const int i = blockIdx.x;
    const int t = threadIdx.x;          // 256
    const int lane = t & 63;
    const int w = t >> 6;
    if (t == 0) { pcnt = 0; ncnt = 0; }
    __syncthreads();
    const unsigned mi = masks[i];
    const float* drow = Dm + (size_t)i * BN;
    const unsigned long long ltmask = (1ull << lane) - 1ull;

    for (int j = t; j < BN; j += 256) {           // all 64 lanes active
        float dj = drow[j];
        bool isp = (mi & masks[j]) != 0u;
        unsigned long long bal = __ballot(isp);
        int np = __popcll(bal);
        if (np > 0) {
            int ldr = __ffsll((unsigned long long)bal) - 1;
            int base = 0;
            if (lane == ldr) base = atomicAdd(&pcnt, np);
            base = __shfl(base, ldr);
            if (isp) pos[base + __popcll(bal & ltmask)] = dj;
        }
        unsigned long long nbal = ~bal;
        int nn = 64 - np;
        if (nn > 0) {
            int ldr = __ffsll((unsigned long long)nbal) - 1;
            int base = 0;
            if (lane == ldr) base = atomicAdd(&ncnt, nn);
            base = __shfl(base, ldr);
            if (!isp) neg[base + __popcll(nbal & ltmask)] = dj;
        }
    }
    __syncthreads();

    const int P = pcnt, N = ncnt;
    float sum = 0.f;
    unsigned cnt = 0;
    for (int p = t; p < P; p += 256) {
        float a = pos[p];
        for (int n = 0; n < N; n++) {
            float v = a - neg[n];
            sum += fmaxf(v, 0.0f);
            cnt += (v > 1e-16f) ? 1u : 0u;
        }
    }
#pragma unroll
    for (int off = 32; off > 0; off >>= 1) {
        sum += __shfl_down(sum, off);
        cnt += __shfl_down(cnt, off);
    }
    if (lane == 0) { wsum[w] = sum; wcnt[w] = cnt; }
    __syncthreads();
    if (t == 0) {
        sum = wsum[0] + wsum[1] + wsum[2] + wsum[3];
        cnt = wcnt[0] + wcnt[1] + wcnt[2] + wcnt[3];
        atomicAdd(&accum[0], sum);
        atomicAdd(&((unsigned*)accum)[1], cnt);
        __threadfence();
        unsigned old = atomicAdd(&((unsigned*)accum)[2], 1u);
        if (old == (unsigned)(gridDim.x - 1)) {   // last block: finalize
            float s   = atomicAdd(&accum[0], 0.0f);
            unsigned c = atomicAdd(&((unsigned*)accum)[1], 0u);
            out[0] = s / ((float)c + 1e-16f);
        }
    }
}

extern "C" void kernel_launch(void* const* d_in, const int* in_sizes, int n_in,
                              void* d_out, int out_size, void* d_ws, size_t ws_size,
                              hipStream_t stream) {
    const float* src    = (const float*)d_in[0];
    const int*   labels = (const int*)d_in[1];
    float* ws = (float*)d_ws;
    unsigned* masks = (unsigned*)ws;
    float*    Dm    = ws + BN;
    float*    accum = ws + BN + (size_t)BN * BN;

    hipLaunchKernelGGL(dist_prep_kernel,     dim3(16, 16), dim3(256), 0, stream,
                       src, labels, masks, Dm, accum);
    hipLaunchKernelGGL(triplet_final_kernel, dim3(BN),     dim3(256), 0, stream,
                       Dm, masks, accum, (float*)d_out);
}